// Round 1
// baseline (656.413 us; speedup 1.0000x reference)
//
#include <hip/hip_runtime.h>

#define N_NODES 100000
#define N_EDGES 1200000
#define DIM 64

// One wave (64 lanes) per edge; lane = feature index.
// Coalesced 256B read of x[src][:], 64 fp32 atomics into msg[dst][:].
__global__ __launch_bounds__(256) void scatter_mean_kernel(
    const float* __restrict__ x, const int* __restrict__ src,
    const int* __restrict__ dst, float* __restrict__ msg,
    float* __restrict__ deg, int n_edges)
{
    long gtid = (long)blockIdx.x * blockDim.x + threadIdx.x;
    int e = (int)(gtid >> 6);
    int lane = threadIdx.x & 63;
    if (e >= n_edges) return;
    int s = src[e];   // wave-uniform load (broadcast)
    int d = dst[e];
    float v = x[(size_t)s * DIM + lane];
    atomicAdd(&msg[(size_t)d * DIM + lane], v);
    if (lane == 0) atomicAdd(&deg[d], 1.0f);
}

// One wave per node: h = msg/max(deg,1); out = h @ W^T + b.
// W staged transposed in LDS: Wt[f][o]; lanes read consecutive o -> 2-way
// bank alias (free on CDNA4).
__global__ __launch_bounds__(256) void finish_kernel(
    const float* __restrict__ msg, const float* __restrict__ deg,
    const float* __restrict__ W, const float* __restrict__ b,
    float* __restrict__ out, int n_nodes)
{
    __shared__ float Wt[DIM][DIM];   // Wt[f][o] = W[o*DIM + f]
    __shared__ float bs[DIM];
    for (int i = threadIdx.x; i < DIM * DIM; i += blockDim.x) {
        int o = i >> 6, f = i & 63;
        Wt[f][o] = W[i];
    }
    if (threadIdx.x < DIM) bs[threadIdx.x] = b[threadIdx.x];
    __syncthreads();

    int wid = blockIdx.x * (blockDim.x >> 6) + (threadIdx.x >> 6);
    int lane = threadIdx.x & 63;
    if (wid >= n_nodes) return;

    float d = deg[wid];
    float inv = 1.0f / fmaxf(d, 1.0f);
    float h = msg[(size_t)wid * DIM + lane] * inv;

    float acc = bs[lane];
    #pragma unroll
    for (int f = 0; f < DIM; ++f) {
        float hf = __shfl(h, f, 64);
        acc = fmaf(hf, Wt[f][lane], acc);
    }
    out[(size_t)wid * DIM + lane] = acc;
}

extern "C" void kernel_launch(void* const* d_in, const int* in_sizes, int n_in,
                              void* d_out, int out_size, void* d_ws, size_t ws_size,
                              hipStream_t stream) {
    const float* x   = (const float*)d_in[0];
    const int*   src = (const int*)d_in[1];
    const int*   dst = (const int*)d_in[2];
    const float* W   = (const float*)d_in[3];
    const float* b   = (const float*)d_in[4];
    float* out = (float*)d_out;

    float* msg = (float*)d_ws;                       // [N_NODES][DIM]
    float* deg = msg + (size_t)N_NODES * DIM;        // [N_NODES]

    size_t zero_bytes = ((size_t)N_NODES * DIM + N_NODES) * sizeof(float);
    hipMemsetAsync(d_ws, 0, zero_bytes, stream);

    // Scatter: one wave per edge -> N_EDGES*64 threads.
    long total_threads = (long)N_EDGES * 64;
    int blocks1 = (int)((total_threads + 255) / 256);
    scatter_mean_kernel<<<blocks1, 256, 0, stream>>>(x, src, dst, msg, deg, N_EDGES);

    // Finish: one wave per node, 4 waves per block.
    int blocks2 = (N_NODES + 3) / 4;
    finish_kernel<<<blocks2, 256, 0, stream>>>(msg, deg, W, b, out, N_NODES);
}

// Round 2
// 321.300 us; speedup vs baseline: 2.0430x; 2.0430x over previous
//
#include <hip/hip_runtime.h>

#define N_NODES 100000
#define N_EDGES 1200000
#define DIM 64
#define SCAN_B 256

// ---------- CSR build ----------

__global__ __launch_bounds__(256) void hist_kernel(
    const int* __restrict__ dst, int* __restrict__ counts, int n)
{
    int i = blockIdx.x * blockDim.x + threadIdx.x;
    if (i < n) atomicAdd(&counts[dst[i]], 1);
}

// Per-block exclusive scan of counts -> offsets (block-local), block total -> blockSums.
__global__ __launch_bounds__(SCAN_B) void scan1_kernel(
    const int* __restrict__ counts, int* __restrict__ offsets,
    int* __restrict__ blockSums, int n)
{
    __shared__ int tmp[SCAN_B];
    int i = blockIdx.x * SCAN_B + threadIdx.x;
    int v = (i < n) ? counts[i] : 0;
    tmp[threadIdx.x] = v;
    __syncthreads();
    #pragma unroll
    for (int d = 1; d < SCAN_B; d <<= 1) {
        int t = (threadIdx.x >= d) ? tmp[threadIdx.x - d] : 0;
        __syncthreads();
        tmp[threadIdx.x] += t;
        __syncthreads();
    }
    if (i < n) offsets[i] = tmp[threadIdx.x] - v;   // exclusive
    if (threadIdx.x == SCAN_B - 1) blockSums[blockIdx.x] = tmp[SCAN_B - 1];
}

// Exclusive scan of blockSums (nb <= 512), single block of 512 threads.
__global__ __launch_bounds__(512) void scan2_kernel(int* __restrict__ blockSums, int nb)
{
    __shared__ int tmp[512];
    int i = threadIdx.x;
    int v = (i < nb) ? blockSums[i] : 0;
    tmp[i] = v;
    __syncthreads();
    #pragma unroll
    for (int d = 1; d < 512; d <<= 1) {
        int t = (i >= d) ? tmp[i - d] : 0;
        __syncthreads();
        tmp[i] += t;
        __syncthreads();
    }
    if (i < nb) blockSums[i] = tmp[i] - v;          // exclusive
}

// Add scanned block bases; also initialize cursor = offsets.
__global__ __launch_bounds__(SCAN_B) void scan3_kernel(
    int* __restrict__ offsets, const int* __restrict__ blockSums,
    int* __restrict__ cursor, int n)
{
    int i = blockIdx.x * SCAN_B + threadIdx.x;
    if (i < n) {
        int o = offsets[i] + blockSums[blockIdx.x];
        offsets[i] = o;
        cursor[i] = o;
    }
}

__global__ __launch_bounds__(256) void fill_kernel(
    const int* __restrict__ src, const int* __restrict__ dst,
    int* __restrict__ cursor, int* __restrict__ csr_src, int n)
{
    int i = blockIdx.x * blockDim.x + threadIdx.x;
    if (i < n) {
        int d = dst[i];
        int pos = atomicAdd(&cursor[d], 1);
        csr_src[pos] = src[i];
    }
}

// ---------- fused pull-aggregate + linear ----------
// One wave per node. Gather x rows via CSR (L2/L3-resident), mean, then
// out = h @ W^T + b with W in LDS (stride 68 -> b128 reads hit all 32 banks)
// and h broadcast via uniform-address ds_read_b128 (free broadcast).
__global__ __launch_bounds__(256) void aggregate_linear_kernel(
    const float* __restrict__ x, const int* __restrict__ csr_src,
    const int* __restrict__ offsets, const int* __restrict__ counts,
    const float* __restrict__ W, const float* __restrict__ b,
    float* __restrict__ out, int n_nodes)
{
    __shared__ float Ws[DIM][68];   // Ws[o][f] = W[o*64+f]; stride 68 words (16B-aligned, all banks)
    __shared__ float bs[DIM];
    __shared__ float hs[4][DIM];

    for (int i = threadIdx.x; i < DIM * DIM; i += 256) {
        Ws[i >> 6][i & 63] = W[i];  // coalesced global read; LDS write consecutive -> conflict-free
    }
    if (threadIdx.x < DIM) bs[threadIdx.x] = b[threadIdx.x];
    __syncthreads();

    int w    = threadIdx.x >> 6;
    int lane = threadIdx.x & 63;
    int node = blockIdx.x * 4 + w;
    if (node >= n_nodes) return;

    int off = offsets[node];
    int deg = counts[node];
    float a0 = 0.f, a1 = 0.f;
    int k = off, end = off + deg;
    for (; k + 1 < end; k += 2) {          // unroll-2: two independent gathers in flight
        int s0 = csr_src[k];
        int s1 = csr_src[k + 1];
        a0 += x[(size_t)s0 * DIM + lane];
        a1 += x[(size_t)s1 * DIM + lane];
    }
    if (k < end) a0 += x[(size_t)csr_src[k] * DIM + lane];
    float h = (a0 + a1) / fmaxf((float)deg, 1.0f);

    hs[w][lane] = h;                        // wave-local: same wave writes then reads, DS in-order
    __builtin_amdgcn_wave_barrier();        // pin ordering at compile time

    float acc = bs[lane];
    #pragma unroll
    for (int f0 = 0; f0 < DIM; f0 += 4) {
        float4 hv = *(const float4*)&hs[w][f0];     // broadcast (uniform address)
        float4 wv = *(const float4*)&Ws[lane][f0];  // stride-68: balanced across banks
        acc = fmaf(hv.x, wv.x, acc);
        acc = fmaf(hv.y, wv.y, acc);
        acc = fmaf(hv.z, wv.z, acc);
        acc = fmaf(hv.w, wv.w, acc);
    }
    out[(size_t)node * DIM + lane] = acc;
}

extern "C" void kernel_launch(void* const* d_in, const int* in_sizes, int n_in,
                              void* d_out, int out_size, void* d_ws, size_t ws_size,
                              hipStream_t stream) {
    const float* x   = (const float*)d_in[0];
    const int*   src = (const int*)d_in[1];
    const int*   dst = (const int*)d_in[2];
    const float* W   = (const float*)d_in[3];
    const float* b   = (const float*)d_in[4];
    float* out = (float*)d_out;

    // workspace layout (ints)
    int* counts    = (int*)d_ws;            // [100032]
    int* offsets   = counts + 100032;       // [100032]
    int* cursor    = offsets + 100032;      // [100032]
    int* blockSums = cursor + 100032;       // [512]
    int* csr_src   = blockSums + 512;       // [1200000]

    hipMemsetAsync(counts, 0, (size_t)N_NODES * sizeof(int), stream);

    int eb = (N_EDGES + 255) / 256;
    int nb = (N_NODES + SCAN_B - 1) / SCAN_B;   // 391 <= 512

    hist_kernel <<<eb, 256, 0, stream>>>(dst, counts, N_EDGES);
    scan1_kernel<<<nb, SCAN_B, 0, stream>>>(counts, offsets, blockSums, N_NODES);
    scan2_kernel<<<1, 512, 0, stream>>>(blockSums, nb);
    scan3_kernel<<<nb, SCAN_B, 0, stream>>>(offsets, blockSums, cursor, N_NODES);
    fill_kernel <<<eb, 256, 0, stream>>>(src, dst, cursor, csr_src, N_EDGES);

    // one wave per node, 4 waves/block; 25000*4 == 100000 exactly
    aggregate_linear_kernel<<<(N_NODES + 3) / 4, 256, 0, stream>>>(
        x, csr_src, offsets, counts, W, b, out, N_NODES);
}

// Round 3
// 312.482 us; speedup vs baseline: 2.1006x; 1.0282x over previous
//
#include <hip/hip_runtime.h>

#define N_NODES 100000
#define N_EDGES 1200000
#define DIM 64

// ---------- CSR build (3 kernels) ----------

__global__ __launch_bounds__(256) void hist_kernel(
    const int* __restrict__ dst, int* __restrict__ counts, int n)
{
    int i = blockIdx.x * blockDim.x + threadIdx.x;
    if (i < n) atomicAdd(&counts[dst[i]], 1);
}

// One kernel replaces scan1+scan2+scan3: block-local LDS scan + atomic block
// base. Bucket order across blocks is non-deterministic, which is fine — the
// gather only needs each node to know its own [offset, offset+count) range.
__global__ __launch_bounds__(256) void offsets_kernel(
    const int* __restrict__ counts, int* __restrict__ offsets,
    int* __restrict__ cursor, int* __restrict__ base_counter, int n)
{
    __shared__ int tmp[256];
    __shared__ int base;
    int i = blockIdx.x * 256 + threadIdx.x;
    int v = (i < n) ? counts[i] : 0;
    tmp[threadIdx.x] = v;
    __syncthreads();
    #pragma unroll
    for (int d = 1; d < 256; d <<= 1) {
        int t = (threadIdx.x >= d) ? tmp[threadIdx.x - d] : 0;
        __syncthreads();
        tmp[threadIdx.x] += t;
        __syncthreads();
    }
    if (threadIdx.x == 255) base = atomicAdd(base_counter, tmp[255]);
    __syncthreads();
    if (i < n) {
        int o = base + tmp[threadIdx.x] - v;   // exclusive within block + base
        offsets[i] = o;
        cursor[i] = o;
    }
}

__global__ __launch_bounds__(256) void fill_kernel(
    const int* __restrict__ src, const int* __restrict__ dst,
    int* __restrict__ cursor, int* __restrict__ csr_src, int n)
{
    int i = blockIdx.x * blockDim.x + threadIdx.x;
    if (i < n) {
        int d = dst[i];
        int pos = atomicAdd(&cursor[d], 1);
        csr_src[pos] = src[i];
    }
}

// ---------- fused pull-aggregate + linear ----------
// One wave per node, lane = feature. Unroll-4 gather for latency hiding.
__global__ __launch_bounds__(256) void aggregate_linear_kernel(
    const float* __restrict__ x, const int* __restrict__ csr_src,
    const int* __restrict__ offsets, const int* __restrict__ counts,
    const float* __restrict__ W, const float* __restrict__ b,
    float* __restrict__ out, int n_nodes)
{
    __shared__ float Ws[DIM][68];   // stride 68 words -> b128 reads hit all banks
    __shared__ float bs[DIM];
    __shared__ float hs[4][DIM];

    for (int i = threadIdx.x; i < DIM * DIM; i += 256) {
        Ws[i >> 6][i & 63] = W[i];
    }
    if (threadIdx.x < DIM) bs[threadIdx.x] = b[threadIdx.x];
    __syncthreads();

    int w    = threadIdx.x >> 6;
    int lane = threadIdx.x & 63;
    int node = blockIdx.x * 4 + w;
    if (node >= n_nodes) return;

    int off = offsets[node];
    int deg = counts[node];
    int end = off + deg;
    float a0 = 0.f, a1 = 0.f, a2 = 0.f, a3 = 0.f;
    int k = off;
    for (; k + 3 < end; k += 4) {          // 4 independent gathers in flight
        int s0 = csr_src[k];
        int s1 = csr_src[k + 1];
        int s2 = csr_src[k + 2];
        int s3 = csr_src[k + 3];
        a0 += x[(size_t)s0 * DIM + lane];
        a1 += x[(size_t)s1 * DIM + lane];
        a2 += x[(size_t)s2 * DIM + lane];
        a3 += x[(size_t)s3 * DIM + lane];
    }
    for (; k < end; ++k) a0 += x[(size_t)csr_src[k] * DIM + lane];
    float h = ((a0 + a1) + (a2 + a3)) / fmaxf((float)deg, 1.0f);

    hs[w][lane] = h;                        // wave-local write then uniform read
    __builtin_amdgcn_wave_barrier();

    float acc = bs[lane];
    #pragma unroll
    for (int f0 = 0; f0 < DIM; f0 += 4) {
        float4 hv = *(const float4*)&hs[w][f0];     // broadcast (uniform addr)
        float4 wv = *(const float4*)&Ws[lane][f0];  // conflict-balanced
        acc = fmaf(hv.x, wv.x, acc);
        acc = fmaf(hv.y, wv.y, acc);
        acc = fmaf(hv.z, wv.z, acc);
        acc = fmaf(hv.w, wv.w, acc);
    }
    out[(size_t)node * DIM + lane] = acc;
}

extern "C" void kernel_launch(void* const* d_in, const int* in_sizes, int n_in,
                              void* d_out, int out_size, void* d_ws, size_t ws_size,
                              hipStream_t stream) {
    const float* x   = (const float*)d_in[0];
    const int*   src = (const int*)d_in[1];
    const int*   dst = (const int*)d_in[2];
    const float* W   = (const float*)d_in[3];
    const float* b   = (const float*)d_in[4];
    float* out = (float*)d_out;

    // workspace layout (ints)
    int* counts       = (int*)d_ws;             // [100032]
    int* base_counter = counts + 100032;        // [32] (only [0] used)
    int* offsets      = base_counter + 32;      // [100032]
    int* cursor       = offsets + 100032;       // [100032]
    int* csr_src      = cursor + 100032;        // [1200000]

    // zero counts + base_counter in one memset
    hipMemsetAsync(counts, 0, (size_t)(100032 + 32) * sizeof(int), stream);

    int eb = (N_EDGES + 255) / 256;
    int nb = (N_NODES + 255) / 256;

    hist_kernel   <<<eb, 256, 0, stream>>>(dst, counts, N_EDGES);
    offsets_kernel<<<nb, 256, 0, stream>>>(counts, offsets, cursor, base_counter, N_NODES);
    fill_kernel   <<<eb, 256, 0, stream>>>(src, dst, cursor, csr_src, N_EDGES);

    aggregate_linear_kernel<<<(N_NODES + 3) / 4, 256, 0, stream>>>(
        x, csr_src, offsets, counts, W, b, out, N_NODES);
}

// Round 4
// 225.233 us; speedup vs baseline: 2.9144x; 1.3874x over previous
//
#include <hip/hip_runtime.h>

#define N_NODES 100000
#define N_EDGES 1200000
#define DIM 64
#define NPW 8          // nodes per wave in aggregate
#define WPB 4          // waves per block

// ---------- CSR build ----------

// 4 edges/thread: count + per-edge rank (atomic return). 1.2M atomics total.
__global__ __launch_bounds__(256) void hist_rank_kernel(
    const int* __restrict__ dst, int* __restrict__ counts,
    int* __restrict__ rank, int n4)
{
    int i = blockIdx.x * blockDim.x + threadIdx.x;
    if (i >= n4) return;
    int4 d = ((const int4*)dst)[i];
    int r0 = atomicAdd(&counts[d.x], 1);
    int r1 = atomicAdd(&counts[d.y], 1);
    int r2 = atomicAdd(&counts[d.z], 1);
    int r3 = atomicAdd(&counts[d.w], 1);
    ((int4*)rank)[i] = make_int4(r0, r1, r2, r3);
}

// Block-local scan + atomic block base (bucket order need not be node order).
__global__ __launch_bounds__(256) void offsets_kernel(
    const int* __restrict__ counts, int* __restrict__ offsets,
    int* __restrict__ base_counter, int n)
{
    __shared__ int tmp[256];
    __shared__ int base;
    int i = blockIdx.x * 256 + threadIdx.x;
    int v = (i < n) ? counts[i] : 0;
    tmp[threadIdx.x] = v;
    __syncthreads();
    #pragma unroll
    for (int d = 1; d < 256; d <<= 1) {
        int t = (threadIdx.x >= d) ? tmp[threadIdx.x - d] : 0;
        __syncthreads();
        tmp[threadIdx.x] += t;
        __syncthreads();
    }
    if (threadIdx.x == 255) base = atomicAdd(base_counter, tmp[255]);
    __syncthreads();
    if (i < n) offsets[i] = base + tmp[threadIdx.x] - v;
}

// Atomic-free scatter: pos = offsets[dst] + rank. Pure bandwidth.
__global__ __launch_bounds__(256) void fill_kernel(
    const int* __restrict__ src, const int* __restrict__ dst,
    const int* __restrict__ rank, const int* __restrict__ offsets,
    int* __restrict__ csr_src, int n4)
{
    int i = blockIdx.x * blockDim.x + threadIdx.x;
    if (i >= n4) return;
    int4 s = ((const int4*)src)[i];
    int4 d = ((const int4*)dst)[i];
    int4 r = ((const int4*)rank)[i];
    csr_src[offsets[d.x] + r.x] = s.x;
    csr_src[offsets[d.y] + r.y] = s.y;
    csr_src[offsets[d.z] + r.z] = s.z;
    csr_src[offsets[d.w] + r.w] = s.w;
}

// ---------- fused pull-aggregate + linear ----------
// One wave handles NPW nodes (amortizes W staging 8x). Lane = feature.
__global__ __launch_bounds__(256) void aggregate_linear_kernel(
    const float* __restrict__ x, const int* __restrict__ csr_src,
    const int* __restrict__ offsets, const int* __restrict__ counts,
    const float* __restrict__ W, const float* __restrict__ bias,
    float* __restrict__ out, int n_nodes)
{
    __shared__ float Ws[DIM][68];   // stride 68 words -> b128 reads hit all banks
    __shared__ float hs[WPB][DIM];

    // float4 staging: 1024 float4, 4 per thread
    for (int i = threadIdx.x; i < DIM * DIM / 4; i += 256) {
        float4 wv = ((const float4*)W)[i];
        int o = (i * 4) >> 6, f = (i * 4) & 63;
        *(float4*)&Ws[o][f] = wv;
    }
    __syncthreads();

    int w    = threadIdx.x >> 6;
    int lane = threadIdx.x & 63;
    float bl = bias[lane];          // L1-cached broadcast-ish read

    int node0 = (blockIdx.x * WPB + w) * NPW;
    #pragma unroll 1
    for (int ni = 0; ni < NPW; ++ni) {
        int node = node0 + ni;
        if (node >= n_nodes) break;

        int off = offsets[node];
        int deg = counts[node];
        int end = off + deg;
        float a0 = 0.f, a1 = 0.f, a2 = 0.f, a3 = 0.f;
        int k = off;
        for (; k + 3 < end; k += 4) {       // 4 gathers in flight
            int s0 = csr_src[k];
            int s1 = csr_src[k + 1];
            int s2 = csr_src[k + 2];
            int s3 = csr_src[k + 3];
            a0 += x[(size_t)s0 * DIM + lane];
            a1 += x[(size_t)s1 * DIM + lane];
            a2 += x[(size_t)s2 * DIM + lane];
            a3 += x[(size_t)s3 * DIM + lane];
        }
        for (; k < end; ++k) a0 += x[(size_t)csr_src[k] * DIM + lane];
        float h = ((a0 + a1) + (a2 + a3)) / fmaxf((float)deg, 1.0f);

        hs[w][lane] = h;                    // wave-local write, uniform-addr reads
        __builtin_amdgcn_wave_barrier();

        float acc = bl;
        #pragma unroll
        for (int f0 = 0; f0 < DIM; f0 += 4) {
            float4 hv = *(const float4*)&hs[w][f0];     // broadcast (free)
            float4 wv = *(const float4*)&Ws[lane][f0];  // conflict-balanced
            acc = fmaf(hv.x, wv.x, acc);
            acc = fmaf(hv.y, wv.y, acc);
            acc = fmaf(hv.z, wv.z, acc);
            acc = fmaf(hv.w, wv.w, acc);
        }
        out[(size_t)node * DIM + lane] = acc;
        __builtin_amdgcn_wave_barrier();    // order hs reads before next write
    }
}

extern "C" void kernel_launch(void* const* d_in, const int* in_sizes, int n_in,
                              void* d_out, int out_size, void* d_ws, size_t ws_size,
                              hipStream_t stream) {
    const float* x   = (const float*)d_in[0];
    const int*   src = (const int*)d_in[1];
    const int*   dst = (const int*)d_in[2];
    const float* W   = (const float*)d_in[3];
    const float* b   = (const float*)d_in[4];
    float* out = (float*)d_out;

    // workspace layout (ints): ~10.4 MB (round-1 proved ws >= 26 MB)
    int* counts       = (int*)d_ws;             // [100032]
    int* base_counter = counts + 100032;        // [32]
    int* offsets      = base_counter + 32;      // [100032]
    int* rank         = offsets + 100032;       // [1200000]
    int* csr_src      = rank + N_EDGES;         // [1200000]

    hipMemsetAsync(counts, 0, (size_t)(100032 + 32) * sizeof(int), stream);

    int n4 = N_EDGES / 4;                       // 300000, exact
    int eb4 = (n4 + 255) / 256;
    int nb = (N_NODES + 255) / 256;

    hist_rank_kernel<<<eb4, 256, 0, stream>>>(dst, counts, rank, n4);
    offsets_kernel  <<<nb, 256, 0, stream>>>(counts, offsets, base_counter, N_NODES);
    fill_kernel     <<<eb4, 256, 0, stream>>>(src, dst, rank, offsets, csr_src, n4);

    // 32 nodes/block: 3125 blocks exactly covers 100000
    int blocks = (N_NODES + WPB * NPW - 1) / (WPB * NPW);
    aggregate_linear_kernel<<<blocks, 256, 0, stream>>>(
        x, csr_src, offsets, counts, W, b, out, N_NODES);
}

// Round 5
// 214.163 us; speedup vs baseline: 3.0650x; 1.0517x over previous
//
#include <hip/hip_runtime.h>

#define N_NODES 100000
#define N_EDGES 1200000
#define DIM 64
#define NPW 8          // nodes per wave in aggregate
#define WPB 4          // waves per block

// ---------- CSR build ----------

// 8 edges/thread: count + per-edge rank (atomic return).
__global__ __launch_bounds__(256) void hist_rank_kernel(
    const int* __restrict__ dst, int* __restrict__ counts,
    int* __restrict__ rank, int n8)
{
    int i = blockIdx.x * blockDim.x + threadIdx.x;
    if (i >= n8) return;
    int4 d0 = ((const int4*)dst)[2 * i];
    int4 d1 = ((const int4*)dst)[2 * i + 1];
    int4 r0, r1;
    r0.x = atomicAdd(&counts[d0.x], 1);
    r0.y = atomicAdd(&counts[d0.y], 1);
    r0.z = atomicAdd(&counts[d0.z], 1);
    r0.w = atomicAdd(&counts[d0.w], 1);
    r1.x = atomicAdd(&counts[d1.x], 1);
    r1.y = atomicAdd(&counts[d1.y], 1);
    r1.z = atomicAdd(&counts[d1.z], 1);
    r1.w = atomicAdd(&counts[d1.w], 1);
    ((int4*)rank)[2 * i]     = r0;
    ((int4*)rank)[2 * i + 1] = r1;
}

// Block-local scan + atomic block base (bucket order need not be node order).
__global__ __launch_bounds__(256) void offsets_kernel(
    const int* __restrict__ counts, int* __restrict__ offsets,
    int* __restrict__ base_counter, int n)
{
    __shared__ int tmp[256];
    __shared__ int base;
    int i = blockIdx.x * 256 + threadIdx.x;
    int v = (i < n) ? counts[i] : 0;
    tmp[threadIdx.x] = v;
    __syncthreads();
    #pragma unroll
    for (int d = 1; d < 256; d <<= 1) {
        int t = (threadIdx.x >= d) ? tmp[threadIdx.x - d] : 0;
        __syncthreads();
        tmp[threadIdx.x] += t;
        __syncthreads();
    }
    if (threadIdx.x == 255) base = atomicAdd(base_counter, tmp[255]);
    __syncthreads();
    if (i < n) offsets[i] = base + tmp[threadIdx.x] - v;
}

// Atomic-free scatter: pos = offsets[dst] + rank. 8 edges/thread.
__global__ __launch_bounds__(256) void fill_kernel(
    const int* __restrict__ src, const int* __restrict__ dst,
    const int* __restrict__ rank, const int* __restrict__ offsets,
    int* __restrict__ csr_src, int n8)
{
    int i = blockIdx.x * blockDim.x + threadIdx.x;
    if (i >= n8) return;
    int4 s0 = ((const int4*)src)[2 * i];
    int4 s1 = ((const int4*)src)[2 * i + 1];
    int4 d0 = ((const int4*)dst)[2 * i];
    int4 d1 = ((const int4*)dst)[2 * i + 1];
    int4 r0 = ((const int4*)rank)[2 * i];
    int4 r1 = ((const int4*)rank)[2 * i + 1];
    csr_src[offsets[d0.x] + r0.x] = s0.x;
    csr_src[offsets[d0.y] + r0.y] = s0.y;
    csr_src[offsets[d0.z] + r0.z] = s0.z;
    csr_src[offsets[d0.w] + r0.w] = s0.w;
    csr_src[offsets[d1.x] + r1.x] = s1.x;
    csr_src[offsets[d1.y] + r1.y] = s1.y;
    csr_src[offsets[d1.z] + r1.z] = s1.z;
    csr_src[offsets[d1.w] + r1.w] = s1.w;
}

// ---------- fused pull-aggregate + linear ----------
// One wave per NPW nodes. Quarter-wave gather: 16 lanes x float4 per row ->
// 4 rows per load instruction, 2 groups unrolled -> 8 rows in flight.
__global__ __launch_bounds__(256) void aggregate_linear_kernel(
    const float* __restrict__ x, const int* __restrict__ csr_src,
    const int* __restrict__ offsets, const int* __restrict__ counts,
    const float* __restrict__ W, const float* __restrict__ bias,
    float* __restrict__ out, int n_nodes)
{
    __shared__ float Ws[DIM][68];   // stride 68 words: b128 reads conflict-free
    __shared__ float hs[WPB][DIM];

    for (int i = threadIdx.x; i < DIM * DIM / 4; i += 256) {
        float4 wv = ((const float4*)W)[i];
        int o = i >> 4, fq = i & 15;        // element i*4 = (o, fq*4)
        *(float4*)&Ws[o][fq * 4] = wv;
    }
    __syncthreads();

    int w    = threadIdx.x >> 6;
    int lane = threadIdx.x & 63;
    int g    = lane >> 4;          // edge-group 0..3 within wave
    int gl   = lane & 15;          // feature-quad index: features gl*4..gl*4+3
    float bl = bias[lane];

    int node0 = (blockIdx.x * WPB + w) * NPW;
    #pragma unroll 1
    for (int ni = 0; ni < NPW; ++ni) {
        int node = node0 + ni;
        if (node >= n_nodes) break;   // grid exact (3125*32=100000); safety only

        int off = offsets[node];
        int deg = counts[node];
        int end = off + deg;
        float4 a0 = {0.f, 0.f, 0.f, 0.f};
        float4 a1 = {0.f, 0.f, 0.f, 0.f};
        for (int k = off; k < end; k += 8) {   // 8 edges per iteration
            int e0 = k + g, e1 = k + 4 + g;
            int s0 = csr_src[min(e0, end - 1)];
            int s1 = csr_src[min(e1, end - 1)];
            float4 v0 = *(const float4*)&x[(size_t)s0 * DIM + gl * 4];
            float4 v1 = *(const float4*)&x[(size_t)s1 * DIM + gl * 4];
            bool p0 = e0 < end, p1 = e1 < end;
            a0.x += p0 ? v0.x : 0.f;  a0.y += p0 ? v0.y : 0.f;
            a0.z += p0 ? v0.z : 0.f;  a0.w += p0 ? v0.w : 0.f;
            a1.x += p1 ? v1.x : 0.f;  a1.y += p1 ? v1.y : 0.f;
            a1.z += p1 ? v1.z : 0.f;  a1.w += p1 ? v1.w : 0.f;
        }
        a0.x += a1.x; a0.y += a1.y; a0.z += a1.z; a0.w += a1.w;
        // cross-group reduce: groups differ in lane bits 4,5
        a0.x += __shfl_xor(a0.x, 16, 64); a0.x += __shfl_xor(a0.x, 32, 64);
        a0.y += __shfl_xor(a0.y, 16, 64); a0.y += __shfl_xor(a0.y, 32, 64);
        a0.z += __shfl_xor(a0.z, 16, 64); a0.z += __shfl_xor(a0.z, 32, 64);
        a0.w += __shfl_xor(a0.w, 16, 64); a0.w += __shfl_xor(a0.w, 32, 64);

        float inv = 1.0f / fmaxf((float)deg, 1.0f);
        if (g == 0) {   // lanes 0-15 hold the full row; write h as float4
            float4 h4 = {a0.x * inv, a0.y * inv, a0.z * inv, a0.w * inv};
            *(float4*)&hs[w][gl * 4] = h4;
        }
        __builtin_amdgcn_wave_barrier();

        float acc = bl;
        #pragma unroll
        for (int f0 = 0; f0 < DIM; f0 += 4) {
            float4 hv = *(const float4*)&hs[w][f0];     // uniform addr: broadcast
            float4 wv = *(const float4*)&Ws[lane][f0];  // conflict-balanced
            acc = fmaf(hv.x, wv.x, acc);
            acc = fmaf(hv.y, wv.y, acc);
            acc = fmaf(hv.z, wv.z, acc);
            acc = fmaf(hv.w, wv.w, acc);
        }
        __builtin_nontemporal_store(acc, &out[(size_t)node * DIM + lane]);
        __builtin_amdgcn_wave_barrier();    // order hs reads before next write
    }
}

extern "C" void kernel_launch(void* const* d_in, const int* in_sizes, int n_in,
                              void* d_out, int out_size, void* d_ws, size_t ws_size,
                              hipStream_t stream) {
    const float* x   = (const float*)d_in[0];
    const int*   src = (const int*)d_in[1];
    const int*   dst = (const int*)d_in[2];
    const float* W   = (const float*)d_in[3];
    const float* b   = (const float*)d_in[4];
    float* out = (float*)d_out;

    // workspace layout (ints)
    int* counts       = (int*)d_ws;             // [100032]
    int* base_counter = counts + 100032;        // [32]
    int* offsets      = base_counter + 32;      // [100032]
    int* rank         = offsets + 100032;       // [1200000]
    int* csr_src      = rank + N_EDGES;         // [1200000]

    hipMemsetAsync(counts, 0, (size_t)(100032 + 32) * sizeof(int), stream);

    int n8 = N_EDGES / 8;                       // 150000 exact
    int eb8 = (n8 + 255) / 256;
    int nb = (N_NODES + 255) / 256;

    hist_rank_kernel<<<eb8, 256, 0, stream>>>(dst, counts, rank, n8);
    offsets_kernel  <<<nb, 256, 0, stream>>>(counts, offsets, base_counter, N_NODES);
    fill_kernel     <<<eb8, 256, 0, stream>>>(src, dst, rank, offsets, csr_src, n8);

    int blocks = (N_NODES + WPB * NPW - 1) / (WPB * NPW);   // 3125
    aggregate_linear_kernel<<<blocks, 256, 0, stream>>>(
        x, csr_src, offsets, counts, W, b, out, N_NODES);
}